// Round 8
// baseline (336.741 us; speedup 1.0000x reference)
//
#include <hip/hip_runtime.h>
#include <hip/hip_bf16.h>
#include <cstdint>
#include <cstddef>

typedef __bf16 bf16_t;
typedef _Float16 f16_t;
typedef __bf16 bf16x8 __attribute__((ext_vector_type(8)));
typedef float  f32x4  __attribute__((ext_vector_type(4)));
typedef float  f32x16 __attribute__((ext_vector_type(16)));

constexpr int kBatch = 4;
constexpr int kT = 4096;
constexpr int kD = 1024;
constexpr int kM = kBatch * kT;     // 16384 rows
constexpr int kCH = kBatch * kD;    // 4096 scan channels
constexpr int kNC = 128;            // scan chunks
constexpr int kL  = kT / kNC;       // 32 steps per chunk
constexpr int LDS_BYTES = 131072;   // 2 bufs x (A 32K + B 32K)

// ---------------------------------------------------------------- helpers
__device__ __forceinline__ void async16(const bf16_t* g, char* l) {
    __builtin_amdgcn_global_load_lds(
        (const __attribute__((address_space(1))) uint32_t*)g,
        (__attribute__((address_space(3))) uint32_t*)l,
        16, 0, 0);
}

__device__ __forceinline__ float fast_sigmoid(float z) {
    return 1.f / (1.f + __expf(-z));
}
__device__ __forceinline__ float fast_tanh(float z) {
    z = fminf(10.f, fmaxf(-10.f, z));
    float e = __expf(2.f * z);
    return (e - 1.f) / (e + 1.f);
}

// ---------------------------------------------------------------- f32 -> bf16 cast (x)
__global__ void cvt_bf16_kernel(const float* __restrict__ in, bf16_t* __restrict__ out, int n8) {
    int i = blockIdx.x * blockDim.x + threadIdx.x;
    if (i >= n8) return;
    const float4* p = reinterpret_cast<const float4*>(in) + 2 * (size_t)i;
    float4 a = p[0], b = p[1];
    bf16x8 o;
    o[0] = (bf16_t)a.x; o[1] = (bf16_t)a.y; o[2] = (bf16_t)a.z; o[3] = (bf16_t)a.w;
    o[4] = (bf16_t)b.x; o[5] = (bf16_t)b.y; o[6] = (bf16_t)b.z; o[7] = (bf16_t)b.w;
    *reinterpret_cast<bf16x8*>(out + 8 * (size_t)i) = o;
}

// merged cast of the 5 weight matrices (each kD*kD) into contiguous wbf
__global__ void cvtw_kernel(const float* __restrict__ w0, const float* __restrict__ w1,
                            const float* __restrict__ w2, const float* __restrict__ w3,
                            const float* __restrict__ w4, bf16_t* __restrict__ out) {
    const int per = kD * kD / 8;
    int i = blockIdx.x * blockDim.x + threadIdx.x;
    int seg = i / per, j = i - seg * per;
    const float* src = seg == 0 ? w0 : seg == 1 ? w1 : seg == 2 ? w2 : seg == 3 ? w3 : w4;
    const float4* p = reinterpret_cast<const float4*>(src) + 2 * (size_t)j;
    float4 a = p[0], b = p[1];
    bf16x8 o;
    o[0] = (bf16_t)a.x; o[1] = (bf16_t)a.y; o[2] = (bf16_t)a.z; o[3] = (bf16_t)a.w;
    o[4] = (bf16_t)b.x; o[5] = (bf16_t)b.y; o[6] = (bf16_t)b.z; o[7] = (bf16_t)b.w;
    *reinterpret_cast<bf16x8*>(out + ((size_t)seg * per + j) * 8) = o;
}

// ---------------------------------------------------------------- 256x256 BK=64 GEMM
// R5 min-sync schedule (ONE barrier + one late vmcnt(0) per K-tile; stage
// tile w+1 at top of iter w) with 32x32x16 MFMA.
// LDS half-region (16KB) layout NATIVE to the 32x32 fragment read:
//   byte = mblk*4096 + ks*1024 + lh*512 + row32*16
// so a wave's (m,ks) fragment read is ONE contiguous 1024B block at
// base + lane*16 -- every 8-lane phase sweeps all 32 banks once: zero
// bank conflicts by construction. Staging keeps linear dest (tid*16) and
// inverse-permutes the GLOBAL source instead (goff).
// C/D layout (m74/m101): col=lane&31, row=(reg&3)+8*(reg>>2)+4*(lane>>5).
// EPI: 0 silu->bf16 | 3 f32 nt | 4 slab0 sigmoid->f16 / slab1 sigmoid->bf16 /
//      slab2 tanh->bf16
template<int EPI>
__global__ __launch_bounds__(512, 2)
void gemm256(const bf16_t* __restrict__ A, const bf16_t* __restrict__ Bw,
             const float* __restrict__ bi0, const float* __restrict__ bi1,
             const float* __restrict__ bi2,
             void* __restrict__ out0, void* __restrict__ out1, void* __restrict__ out2,
             int M, int N, int K)
{
    extern __shared__ char lds[];
    const int tid  = threadIdx.x;
    const int lane = tid & 63;
    const int wv   = tid >> 6;
    const int wr   = wv >> 2;      // 0..1  (M waves, 128 rows each)
    const int wc   = wv & 3;       // 0..3  (N waves, 64 cols each)
    const int l32  = lane & 31;
    const int lh   = lane >> 5;    // k-half selector

    // ---- bijective XCD-chunk swizzle (nwg % 8 == 0 for all our grids) ----
    int bid = blockIdx.y * gridDim.x + blockIdx.x;
    int nwg = gridDim.x * gridDim.y;
    int swz = (bid & 7) * (nwg >> 3) + (bid >> 3);
    int gx  = N >> 8;
    int n0  = (swz % gx) << 8;
    int m0  = (swz / gx) << 8;

    // ---- staging: inverse map LDS chunk -> global (row, col) ----
    // chunk c (16B units within a 16KB half-region):
    //   mblk=(c>>8)&3, ks=(c>>6)&3, lh=(c>>5)&1, row=c&31
    auto goff = [&](int chunk) -> size_t {
        int mb = (chunk >> 8) & 3;
        int ks = (chunk >> 6) & 3;
        int hl = (chunk >> 5) & 1;
        int r  = chunk & 31;
        return (size_t)(mb * 32 + r) * K + ks * 16 + hl * 8;
    };
    const size_t g0 = goff(tid), g1 = goff(512 + tid);
    const int d0 = wv << 10, d1 = 8192 + (wv << 10);   // linear LDS dest (wave base)

    auto STAGE = [&](const bf16_t* G, int row0, int k0, int lds_base) {
        const bf16_t* base = G + (size_t)row0 * K + k0;
        async16(base + g0, lds + lds_base + d0);
        async16(base + g1, lds + lds_base + d1);
    };
    auto STAGE_TILE = [&](int w, int bufo) {
        const int k0 = w << 6;
        STAGE(A,  m0,        k0, bufo);
        STAGE(A,  m0 + 128,  k0, bufo + 16384);
        STAGE(Bw, n0,        k0, bufo + 32768);
        STAGE(Bw, n0 + 128,  k0, bufo + 49152);
    };

    // ---- fragment read offsets: contiguous 1024B block per (blk, ks) ----
    const int lane16 = lane << 4;
    int offA[4][4], offB[2][4];
#pragma unroll
    for (int m = 0; m < 4; ++m)
#pragma unroll
        for (int ks = 0; ks < 4; ++ks)
            offA[m][ks] = (m << 12) + (ks << 10) + lane16;
#pragma unroll
    for (int n = 0; n < 2; ++n)
#pragma unroll
        for (int ks = 0; ks < 4; ++ks)
            offB[n][ks] = ((((wc & 1) << 1) + n) << 12) + (ks << 10) + lane16;

    f32x16 acc[4][2];
#pragma unroll
    for (int i = 0; i < 4; ++i)
#pragma unroll
        for (int j = 0; j < 2; ++j)
            acc[i][j] = (f32x16)(0.f);

    const int NT = K >> 6;   // 16

    // ---- prologue: stage tile 0 only ----
    STAGE_TILE(0, 0);
    asm volatile("s_waitcnt vmcnt(0)" ::: "memory");
    asm volatile("s_barrier" ::: "memory");

    for (int w = 0; w < NT; ++w) {
        const int bufo  = (w & 1) << 16;
        const int nbufo = bufo ^ 65536;
        const int aReg = bufo + (wr << 14);                  // A half for this wave
        const int bReg = bufo + 32768 + ((wc >> 1) << 14);   // B half for this wave

        // stage next tile into the buffer whose reads finished last iteration
        if (w + 1 < NT) STAGE_TILE(w + 1, nbufo);

#pragma unroll
        for (int ks = 0; ks < 4; ++ks) {
            bf16x8 aF[4], bF[2];
#pragma unroll
            for (int m = 0; m < 4; ++m)
                aF[m] = *reinterpret_cast<const bf16x8*>(lds + aReg + offA[m][ks]);
#pragma unroll
            for (int n = 0; n < 2; ++n)
                bF[n] = *reinterpret_cast<const bf16x8*>(lds + bReg + offB[n][ks]);
            __builtin_amdgcn_s_setprio(1);
#pragma unroll
            for (int m = 0; m < 4; ++m)
#pragma unroll
                for (int n = 0; n < 2; ++n)
                    acc[m][n] = __builtin_amdgcn_mfma_f32_32x32x16_bf16(aF[m], bF[n], acc[m][n], 0, 0, 0);
            __builtin_amdgcn_s_setprio(0);
        }

        if (w + 1 < NT) {
            // stage of tile w+1 was issued a full K-tile ago -> drain ~free
            asm volatile("s_waitcnt vmcnt(0)" ::: "memory");
            asm volatile("s_barrier" ::: "memory");
        }
    }

    // ---- epilogue: 32x32 C/D layout col=lane&31, row=(reg&3)+8*(reg>>2)+4*lh ----
    const int slab = n0 >> 10;                 // block-uniform (EPI==4)
    const float* bia = (EPI == 4) ? (slab == 0 ? bi0 : slab == 1 ? bi1 : bi2) : nullptr;
#pragma unroll
    for (int nf = 0; nf < 2; ++nf) {
        const int colg = n0 + wc * 64 + nf * 32 + l32;
        const int cL = colg & (kD - 1);
        float bs = 0.f;
        if constexpr (EPI == 4) bs = bia[cL];
#pragma unroll
        for (int mf = 0; mf < 4; ++mf) {
            const int rbase = m0 + wr * 128 + mf * 32 + lh * 4;
#pragma unroll
            for (int rg = 0; rg < 16; ++rg) {
                const int rowg = rbase + (rg & 3) + ((rg >> 2) << 3);
                const float f = acc[mf][nf][rg];
                if constexpr (EPI == 0) {
                    float s = f * fast_sigmoid(f);
                    reinterpret_cast<bf16_t*>(out0)[(size_t)rowg * N + colg] = (bf16_t)s;
                } else if constexpr (EPI == 3) {
                    __builtin_nontemporal_store(f, reinterpret_cast<float*>(out0) + (size_t)rowg * N + colg);
                } else {  // EPI == 4
                    const size_t idx = (size_t)rowg * kD + cL;
                    if (slab == 0) {
                        reinterpret_cast<f16_t*>(out0)[idx] = (f16_t)fast_sigmoid(f + bs);
                    } else if (slab == 1) {
                        reinterpret_cast<bf16_t*>(out1)[idx] = (bf16_t)fast_sigmoid(f + bs);
                    } else {
                        reinterpret_cast<bf16_t*>(out2)[idx] = (bf16_t)fast_tanh(f + bs);
                    }
                }
            }
        }
    }
}

// ---------------------------------------------------------------- chunked linear scan
// h_t = a_t*h + beta_t*v_t ; alpha fp16, beta/v bf16.
__global__ void scan_chunk_kernel(const f16_t* __restrict__ alpha,
                                  const bf16_t* __restrict__ beta,
                                  const bf16_t* __restrict__ vv,
                                  float* __restrict__ Aagg,
                                  float* __restrict__ Bagg)
{
    const int u  = blockIdx.x * blockDim.x + threadIdx.x;
    const int ch = u & (kCH - 1);
    const int c  = u >> 12;
    const int b  = ch >> 10;
    const int d  = ch & (kD - 1);
    size_t base = ((size_t)b * kT + (size_t)c * kL) * kD + d;
    float Ac = 1.f, Bc = 0.f;
#pragma unroll 4
    for (int t = 0; t < kL; ++t) {
        float a  = (float)alpha[base];
        float bv = (float)beta[base] * (float)vv[base];
        Ac *= a;
        Bc = a * Bc + bv;
        base += kD;
    }
    Aagg[u] = Ac;
    Bagg[u] = Bc;
}

__global__ void scan_mid_kernel(const float* __restrict__ Aagg,
                                const float* __restrict__ Bagg,
                                float* __restrict__ Hin,
                                float* __restrict__ hlast)
{
    const int ch = blockIdx.x * blockDim.x + threadIdx.x;
    float h = 0.f;
#pragma unroll 8
    for (int c = 0; c < kNC; ++c) {
        Hin[(size_t)c * kCH + ch] = h;
        h = Aagg[(size_t)c * kCH + ch] * h + Bagg[(size_t)c * kCH + ch];
    }
    hlast[ch] = h;
}

__global__ void scan_out_kernel(const f16_t* __restrict__ alpha,
                                const bf16_t* __restrict__ beta,
                                const bf16_t* __restrict__ vv,
                                const float* __restrict__ Hin,
                                bf16_t* __restrict__ cell)
{
    const int u  = blockIdx.x * blockDim.x + threadIdx.x;
    const int ch = u & (kCH - 1);
    const int c  = u >> 12;
    const int b  = ch >> 10;
    const int d  = ch & (kD - 1);
    size_t base = ((size_t)b * kT + (size_t)c * kL) * kD + d;
    float h = Hin[u];
#pragma unroll 4
    for (int t = 0; t < kL; ++t) {
        float a  = (float)alpha[base];
        float bv = (float)beta[base] * (float)vv[base];
        h = a * h + bv;
        float s = 1.f / (1.f + __expf(-h));
        cell[base] = (bf16_t)(h * h * s);
        base += kD;
    }
}

// ---------------------------------------------------------------- launch
extern "C" void kernel_launch(void* const* d_in, const int* in_sizes, int n_in,
                              void* d_out, int out_size, void* d_ws, size_t ws_size,
                              hipStream_t stream)
{
    const float* x     = (const float*)d_in[0];
    const float* W_in  = (const float*)d_in[1];
    const float* W_al  = (const float*)d_in[2];
    const float* b_al  = (const float*)d_in[3];
    const float* W_be  = (const float*)d_in[4];
    const float* b_be  = (const float*)d_in[5];
    const float* W_v   = (const float*)d_in[6];
    const float* b_v   = (const float*)d_in[7];
    const float* W_out = (const float*)d_in[8];

    float* out   = (float*)d_out;
    float* hlast = out + (size_t)kM * kD;

    char* ws = (char*)d_ws;
    size_t off = 0;
    auto alloc = [&](size_t bytes) -> void* {
        void* p = ws + off;
        off += (bytes + 255) & ~(size_t)255;
        return p;
    };
    bf16_t* xbf   = (bf16_t*)alloc((size_t)kM * kD * 2);   // dead after GEMM1 -> cell
    bf16_t* xp    = (bf16_t*)alloc((size_t)kM * kD * 2);   // dead after fused -> aggs
    f16_t*  alpha = (f16_t*) alloc((size_t)kM * kD * 2);
    bf16_t* betab = (bf16_t*)alloc((size_t)kM * kD * 2);
    bf16_t* vb    = (bf16_t*)alloc((size_t)kM * kD * 2);
    bf16_t* wbf   = (bf16_t*)alloc((size_t)5 * kD * kD * 2);

    bf16_t* Winb = wbf;                         // [W_in; W_al; W_be; W_v; W_out]
    bf16_t* Wfus = wbf + 1 * (size_t)kD * kD;   // fused B: rows 0..3071
    bf16_t* Wob  = wbf + 4 * (size_t)kD * kD;

    bf16_t* cell = xbf;
    float*  Aagg = (float*)xp;
    float*  Bagg = Aagg + (size_t)kNC * kCH;
    float*  Hin  = Bagg + (size_t)kNC * kCH;

    hipFuncSetAttribute(reinterpret_cast<const void*>(gemm256<0>), hipFuncAttributeMaxDynamicSharedMemorySize, LDS_BYTES);
    hipFuncSetAttribute(reinterpret_cast<const void*>(gemm256<3>), hipFuncAttributeMaxDynamicSharedMemorySize, LDS_BYTES);
    hipFuncSetAttribute(reinterpret_cast<const void*>(gemm256<4>), hipFuncAttributeMaxDynamicSharedMemorySize, LDS_BYTES);

    // 1) casts to bf16
    {
        int n8 = kM * kD / 8;
        cvt_bf16_kernel<<<(n8 + 255) / 256, 256, 0, stream>>>(x, xbf, n8);
        int wtot = 5 * kD * kD / 8;
        cvtw_kernel<<<(wtot + 255) / 256, 256, 0, stream>>>(W_in, W_al, W_be, W_v, W_out, wbf);
    }

    dim3 grid1(kD / 256, kM / 256);     // (4, 64)  = 256 wgs
    dim3 gridF(3 * kD / 256, kM / 256); // (12, 64) = 768 wgs

    // 2) xp = silu(x @ W_in^T)                       [bf16]
    gemm256<0><<<grid1, 512, LDS_BYTES, stream>>>(xbf, Winb, nullptr, nullptr, nullptr,
                                                  xp, nullptr, nullptr, kM, kD, kD);
    // 3) fused: alpha=sigmoid(+b_al) f16 | beta=sigmoid(+b_be) bf16 | v=tanh(+b_v) bf16
    gemm256<4><<<gridF, 512, LDS_BYTES, stream>>>(xp, Wfus, b_al, b_be, b_v,
                                                  alpha, betab, vb, kM, 3 * kD, kD);
    // 4) chunked scan (bv = beta*v on the fly)
    scan_chunk_kernel<<<kNC * kCH / 256, 256, 0, stream>>>(alpha, betab, vb, Aagg, Bagg);
    scan_mid_kernel<<<kCH / 256, 256, 0, stream>>>(Aagg, Bagg, Hin, hlast);
    scan_out_kernel<<<kNC * kCH / 256, 256, 0, stream>>>(alpha, betab, vb, Hin, cell);

    // 5) output = cell @ W_out^T                     [f32 nt -> d_out]
    gemm256<3><<<grid1, 512, LDS_BYTES, stream>>>(cell, Wob, nullptr, nullptr, nullptr,
                                                  out, nullptr, nullptr, kM, kD, kD);
}

// Round 9
// 322.923 us; speedup vs baseline: 1.0428x; 1.0428x over previous
//
#include <hip/hip_runtime.h>
#include <hip/hip_bf16.h>
#include <cstdint>
#include <cstddef>

typedef __bf16 bf16_t;
typedef _Float16 f16_t;
typedef __bf16 bf16x8 __attribute__((ext_vector_type(8)));
typedef float  f32x4  __attribute__((ext_vector_type(4)));
typedef float  f32x16 __attribute__((ext_vector_type(16)));

constexpr int kBatch = 4;
constexpr int kT = 4096;
constexpr int kD = 1024;
constexpr int kM = kBatch * kT;     // 16384 rows
constexpr int kCH = kBatch * kD;    // 4096 scan channels
constexpr int kNC = 128;            // scan chunks
constexpr int kL  = kT / kNC;       // 32 steps per chunk
constexpr int LDS_BYTES = 131072;   // 2 bufs x (A 32K + B 32K)

// ---------------------------------------------------------------- helpers
__device__ __forceinline__ void async16(const bf16_t* g, char* l) {
    __builtin_amdgcn_global_load_lds(
        (const __attribute__((address_space(1))) uint32_t*)g,
        (__attribute__((address_space(3))) uint32_t*)l,
        16, 0, 0);
}

__device__ __forceinline__ float fast_sigmoid(float z) {
    return 1.f / (1.f + __expf(-z));
}
__device__ __forceinline__ float fast_tanh(float z) {
    z = fminf(10.f, fmaxf(-10.f, z));
    float e = __expf(2.f * z);
    return (e - 1.f) / (e + 1.f);
}

// ---------------------------------------------------------------- f32 -> bf16 cast (x)
__global__ void cvt_bf16_kernel(const float* __restrict__ in, bf16_t* __restrict__ out, int n8) {
    int i = blockIdx.x * blockDim.x + threadIdx.x;
    if (i >= n8) return;
    const float4* p = reinterpret_cast<const float4*>(in) + 2 * (size_t)i;
    float4 a = p[0], b = p[1];
    bf16x8 o;
    o[0] = (bf16_t)a.x; o[1] = (bf16_t)a.y; o[2] = (bf16_t)a.z; o[3] = (bf16_t)a.w;
    o[4] = (bf16_t)b.x; o[5] = (bf16_t)b.y; o[6] = (bf16_t)b.z; o[7] = (bf16_t)b.w;
    *reinterpret_cast<bf16x8*>(out + 8 * (size_t)i) = o;
}

// merged cast of the 5 weight matrices (each kD*kD) into contiguous wbf
__global__ void cvtw_kernel(const float* __restrict__ w0, const float* __restrict__ w1,
                            const float* __restrict__ w2, const float* __restrict__ w3,
                            const float* __restrict__ w4, bf16_t* __restrict__ out) {
    const int per = kD * kD / 8;
    int i = blockIdx.x * blockDim.x + threadIdx.x;
    int seg = i / per, j = i - seg * per;
    const float* src = seg == 0 ? w0 : seg == 1 ? w1 : seg == 2 ? w2 : seg == 3 ? w3 : w4;
    const float4* p = reinterpret_cast<const float4*>(src) + 2 * (size_t)j;
    float4 a = p[0], b = p[1];
    bf16x8 o;
    o[0] = (bf16_t)a.x; o[1] = (bf16_t)a.y; o[2] = (bf16_t)a.z; o[3] = (bf16_t)a.w;
    o[4] = (bf16_t)b.x; o[5] = (bf16_t)b.y; o[6] = (bf16_t)b.z; o[7] = (bf16_t)b.w;
    *reinterpret_cast<bf16x8*>(out + ((size_t)seg * per + j) * 8) = o;
}

// ---------------------------------------------------------------- 256x256 BK=64 GEMM
// R5 min-sync schedule (ONE barrier + one late vmcnt(0) per K-tile; stage
// tile w+1 at top of iter w) with 32x32x16 MFMA.
// LDS half-region (16KB): row-major 128 rows x 128B, with 3-bit chunk XOR:
//   physical 16B-chunk p = logical chunk (ks*2+lh) ^ (row & 7)
// Read phase (8 lanes = 8 consecutive rows, same logical chunk) therefore
// sweeps all 8 bank groups -> zero conflicts. Staging wave: 8 lanes cover one
// full 128B row (chunks permuted within the row) -> global coalescing
// identical to plain row-major. Both sides use the same involution (rule #21).
// C/D layout (m74/m101): col=lane&31, row=(reg&3)+8*(reg>>2)+4*(lane>>5).
// EPI: 0 silu->bf16 | 3 f32 nt | 4 slab0 sigmoid->f16 / slab1 sigmoid->bf16 /
//      slab2 tanh->bf16
template<int EPI>
__global__ __launch_bounds__(512, 2)
void gemm256(const bf16_t* __restrict__ A, const bf16_t* __restrict__ Bw,
             const float* __restrict__ bi0, const float* __restrict__ bi1,
             const float* __restrict__ bi2,
             void* __restrict__ out0, void* __restrict__ out1, void* __restrict__ out2,
             int M, int N, int K)
{
    extern __shared__ char lds[];
    const int tid  = threadIdx.x;
    const int lane = tid & 63;
    const int wv   = tid >> 6;
    const int wr   = wv >> 2;      // 0..1  (M waves, 128 rows each)
    const int wc   = wv & 3;       // 0..3  (N waves, 64 cols each)
    const int l32  = lane & 31;
    const int lh   = lane >> 5;    // k-half selector

    // ---- bijective XCD-chunk swizzle (nwg % 8 == 0 for all our grids) ----
    int bid = blockIdx.y * gridDim.x + blockIdx.x;
    int nwg = gridDim.x * gridDim.y;
    int swz = (bid & 7) * (nwg >> 3) + (bid >> 3);
    int gx  = N >> 8;
    int n0  = (swz % gx) << 8;
    int m0  = (swz / gx) << 8;

    // ---- staging: inverse map LDS chunk -> global (row, col) ----
    // chunk c (16B units in 16KB region): row = c>>3, phys chunk = c&7,
    // logical chunk = (c&7) ^ (row&7)  (involution)
    auto goff = [&](int chunk) -> size_t {
        int r = chunk >> 3;
        int p = (chunk & 7) ^ (r & 7);
        return (size_t)r * K + (p << 3);
    };
    const size_t g0 = goff(tid), g1 = goff(512 + tid);
    const int d0 = wv << 10, d1 = 8192 + (wv << 10);   // linear LDS dest (wave base)

    auto STAGE = [&](const bf16_t* G, int row0, int k0, int lds_base) {
        const bf16_t* base = G + (size_t)row0 * K + k0;
        async16(base + g0, lds + lds_base + d0);
        async16(base + g1, lds + lds_base + d1);
    };
    auto STAGE_TILE = [&](int w, int bufo) {
        const int k0 = w << 6;
        STAGE(A,  m0,        k0, bufo);
        STAGE(A,  m0 + 128,  k0, bufo + 16384);
        STAGE(Bw, n0,        k0, bufo + 32768);
        STAGE(Bw, n0 + 128,  k0, bufo + 49152);
    };

    // ---- fragment read offsets: row = blk*32 + l32, chunk = (ks*2+lh)^(row&7) ----
    int offA[4][4], offB[2][4];
#pragma unroll
    for (int m = 0; m < 4; ++m)
#pragma unroll
        for (int ks = 0; ks < 4; ++ks)
            offA[m][ks] = (m << 12) + (l32 << 7) + ((((ks << 1) | lh) ^ (l32 & 7)) << 4);
#pragma unroll
    for (int n = 0; n < 2; ++n)
#pragma unroll
        for (int ks = 0; ks < 4; ++ks)
            offB[n][ks] = ((wc & 1) << 13) + (n << 12) + (l32 << 7)
                        + ((((ks << 1) | lh) ^ (l32 & 7)) << 4);

    f32x16 acc[4][2];
#pragma unroll
    for (int i = 0; i < 4; ++i)
#pragma unroll
        for (int j = 0; j < 2; ++j)
            acc[i][j] = (f32x16)(0.f);

    const int NT = K >> 6;   // 16

    // ---- prologue: stage tile 0 only ----
    STAGE_TILE(0, 0);
    asm volatile("s_waitcnt vmcnt(0)" ::: "memory");
    asm volatile("s_barrier" ::: "memory");

    for (int w = 0; w < NT; ++w) {
        const int bufo  = (w & 1) << 16;
        const int nbufo = bufo ^ 65536;
        const int aReg = bufo + (wr << 14);                  // A half for this wave
        const int bReg = bufo + 32768 + ((wc >> 1) << 14);   // B half for this wave

        // stage next tile into the buffer whose reads finished last iteration
        if (w + 1 < NT) STAGE_TILE(w + 1, nbufo);

#pragma unroll
        for (int ks = 0; ks < 4; ++ks) {
            bf16x8 aF[4], bF[2];
#pragma unroll
            for (int m = 0; m < 4; ++m)
                aF[m] = *reinterpret_cast<const bf16x8*>(lds + aReg + offA[m][ks]);
#pragma unroll
            for (int n = 0; n < 2; ++n)
                bF[n] = *reinterpret_cast<const bf16x8*>(lds + bReg + offB[n][ks]);
            __builtin_amdgcn_s_setprio(1);
#pragma unroll
            for (int m = 0; m < 4; ++m)
#pragma unroll
                for (int n = 0; n < 2; ++n)
                    acc[m][n] = __builtin_amdgcn_mfma_f32_32x32x16_bf16(aF[m], bF[n], acc[m][n], 0, 0, 0);
            __builtin_amdgcn_s_setprio(0);
        }

        if (w + 1 < NT) {
            // stage of tile w+1 was issued a full K-tile ago -> drain ~free
            asm volatile("s_waitcnt vmcnt(0)" ::: "memory");
            asm volatile("s_barrier" ::: "memory");
        }
    }

    // ---- epilogue: 32x32 C/D layout col=lane&31, row=(reg&3)+8*(reg>>2)+4*lh ----
    const int slab = n0 >> 10;                 // block-uniform (EPI==4)
    const float* bia = (EPI == 4) ? (slab == 0 ? bi0 : slab == 1 ? bi1 : bi2) : nullptr;
#pragma unroll
    for (int nf = 0; nf < 2; ++nf) {
        const int colg = n0 + wc * 64 + nf * 32 + l32;
        const int cL = colg & (kD - 1);
        float bs = 0.f;
        if constexpr (EPI == 4) bs = bia[cL];
#pragma unroll
        for (int mf = 0; mf < 4; ++mf) {
            const int rbase = m0 + wr * 128 + mf * 32 + lh * 4;
#pragma unroll
            for (int rg = 0; rg < 16; ++rg) {
                const int rowg = rbase + (rg & 3) + ((rg >> 2) << 3);
                const float f = acc[mf][nf][rg];
                if constexpr (EPI == 0) {
                    float s = f * fast_sigmoid(f);
                    reinterpret_cast<bf16_t*>(out0)[(size_t)rowg * N + colg] = (bf16_t)s;
                } else if constexpr (EPI == 3) {
                    __builtin_nontemporal_store(f, reinterpret_cast<float*>(out0) + (size_t)rowg * N + colg);
                } else {  // EPI == 4
                    const size_t idx = (size_t)rowg * kD + cL;
                    if (slab == 0) {
                        reinterpret_cast<f16_t*>(out0)[idx] = (f16_t)fast_sigmoid(f + bs);
                    } else if (slab == 1) {
                        reinterpret_cast<bf16_t*>(out1)[idx] = (bf16_t)fast_sigmoid(f + bs);
                    } else {
                        reinterpret_cast<bf16_t*>(out2)[idx] = (bf16_t)fast_tanh(f + bs);
                    }
                }
            }
        }
    }
}

// ---------------------------------------------------------------- chunked linear scan
// h_t = a_t*h + beta_t*v_t ; alpha fp16, beta/v bf16.
__global__ void scan_chunk_kernel(const f16_t* __restrict__ alpha,
                                  const bf16_t* __restrict__ beta,
                                  const bf16_t* __restrict__ vv,
                                  float* __restrict__ Aagg,
                                  float* __restrict__ Bagg)
{
    const int u  = blockIdx.x * blockDim.x + threadIdx.x;
    const int ch = u & (kCH - 1);
    const int c  = u >> 12;
    const int b  = ch >> 10;
    const int d  = ch & (kD - 1);
    size_t base = ((size_t)b * kT + (size_t)c * kL) * kD + d;
    float Ac = 1.f, Bc = 0.f;
#pragma unroll 4
    for (int t = 0; t < kL; ++t) {
        float a  = (float)alpha[base];
        float bv = (float)beta[base] * (float)vv[base];
        Ac *= a;
        Bc = a * Bc + bv;
        base += kD;
    }
    Aagg[u] = Ac;
    Bagg[u] = Bc;
}

__global__ void scan_mid_kernel(const float* __restrict__ Aagg,
                                const float* __restrict__ Bagg,
                                float* __restrict__ Hin,
                                float* __restrict__ hlast)
{
    const int ch = blockIdx.x * blockDim.x + threadIdx.x;
    float h = 0.f;
#pragma unroll 8
    for (int c = 0; c < kNC; ++c) {
        Hin[(size_t)c * kCH + ch] = h;
        h = Aagg[(size_t)c * kCH + ch] * h + Bagg[(size_t)c * kCH + ch];
    }
    hlast[ch] = h;
}

__global__ void scan_out_kernel(const f16_t* __restrict__ alpha,
                                const bf16_t* __restrict__ beta,
                                const bf16_t* __restrict__ vv,
                                const float* __restrict__ Hin,
                                bf16_t* __restrict__ cell)
{
    const int u  = blockIdx.x * blockDim.x + threadIdx.x;
    const int ch = u & (kCH - 1);
    const int c  = u >> 12;
    const int b  = ch >> 10;
    const int d  = ch & (kD - 1);
    size_t base = ((size_t)b * kT + (size_t)c * kL) * kD + d;
    float h = Hin[u];
#pragma unroll 4
    for (int t = 0; t < kL; ++t) {
        float a  = (float)alpha[base];
        float bv = (float)beta[base] * (float)vv[base];
        h = a * h + bv;
        float s = 1.f / (1.f + __expf(-h));
        cell[base] = (bf16_t)(h * h * s);
        base += kD;
    }
}

// ---------------------------------------------------------------- launch
extern "C" void kernel_launch(void* const* d_in, const int* in_sizes, int n_in,
                              void* d_out, int out_size, void* d_ws, size_t ws_size,
                              hipStream_t stream)
{
    const float* x     = (const float*)d_in[0];
    const float* W_in  = (const float*)d_in[1];
    const float* W_al  = (const float*)d_in[2];
    const float* b_al  = (const float*)d_in[3];
    const float* W_be  = (const float*)d_in[4];
    const float* b_be  = (const float*)d_in[5];
    const float* W_v   = (const float*)d_in[6];
    const float* b_v   = (const float*)d_in[7];
    const float* W_out = (const float*)d_in[8];

    float* out   = (float*)d_out;
    float* hlast = out + (size_t)kM * kD;

    char* ws = (char*)d_ws;
    size_t off = 0;
    auto alloc = [&](size_t bytes) -> void* {
        void* p = ws + off;
        off += (bytes + 255) & ~(size_t)255;
        return p;
    };
    bf16_t* xbf   = (bf16_t*)alloc((size_t)kM * kD * 2);   // dead after GEMM1 -> cell
    bf16_t* xp    = (bf16_t*)alloc((size_t)kM * kD * 2);   // dead after fused -> aggs
    f16_t*  alpha = (f16_t*) alloc((size_t)kM * kD * 2);
    bf16_t* betab = (bf16_t*)alloc((size_t)kM * kD * 2);
    bf16_t* vb    = (bf16_t*)alloc((size_t)kM * kD * 2);
    bf16_t* wbf   = (bf16_t*)alloc((size_t)5 * kD * kD * 2);

    bf16_t* Winb = wbf;                         // [W_in; W_al; W_be; W_v; W_out]
    bf16_t* Wfus = wbf + 1 * (size_t)kD * kD;   // fused B: rows 0..3071
    bf16_t* Wob  = wbf + 4 * (size_t)kD * kD;

    bf16_t* cell = xbf;
    float*  Aagg = (float*)xp;
    float*  Bagg = Aagg + (size_t)kNC * kCH;
    float*  Hin  = Bagg + (size_t)kNC * kCH;

    hipFuncSetAttribute(reinterpret_cast<const void*>(gemm256<0>), hipFuncAttributeMaxDynamicSharedMemorySize, LDS_BYTES);
    hipFuncSetAttribute(reinterpret_cast<const void*>(gemm256<3>), hipFuncAttributeMaxDynamicSharedMemorySize, LDS_BYTES);
    hipFuncSetAttribute(reinterpret_cast<const void*>(gemm256<4>), hipFuncAttributeMaxDynamicSharedMemorySize, LDS_BYTES);

    // 1) casts to bf16
    {
        int n8 = kM * kD / 8;
        cvt_bf16_kernel<<<(n8 + 255) / 256, 256, 0, stream>>>(x, xbf, n8);
        int wtot = 5 * kD * kD / 8;
        cvtw_kernel<<<(wtot + 255) / 256, 256, 0, stream>>>(W_in, W_al, W_be, W_v, W_out, wbf);
    }

    dim3 grid1(kD / 256, kM / 256);     // (4, 64)  = 256 wgs
    dim3 gridF(3 * kD / 256, kM / 256); // (12, 64) = 768 wgs

    // 2) xp = silu(x @ W_in^T)                       [bf16]
    gemm256<0><<<grid1, 512, LDS_BYTES, stream>>>(xbf, Winb, nullptr, nullptr, nullptr,
                                                  xp, nullptr, nullptr, kM, kD, kD);
    // 3) fused: alpha=sigmoid(+b_al) f16 | beta=sigmoid(+b_be) bf16 | v=tanh(+b_v) bf16
    gemm256<4><<<gridF, 512, LDS_BYTES, stream>>>(xp, Wfus, b_al, b_be, b_v,
                                                  alpha, betab, vb, kM, 3 * kD, kD);
    // 4) chunked scan (bv = beta*v on the fly)
    scan_chunk_kernel<<<kNC * kCH / 256, 256, 0, stream>>>(alpha, betab, vb, Aagg, Bagg);
    scan_mid_kernel<<<kCH / 256, 256, 0, stream>>>(Aagg, Bagg, Hin, hlast);
    scan_out_kernel<<<kNC * kCH / 256, 256, 0, stream>>>(alpha, betab, vb, Hin, cell);

    // 5) output = cell @ W_out^T                     [f32 nt -> d_out]
    gemm256<3><<<grid1, 512, LDS_BYTES, stream>>>(cell, Wob, nullptr, nullptr, nullptr,
                                                  out, nullptr, nullptr, kM, kD, kD);
}